// Round 1
// baseline (2516.638 us; speedup 1.0000x reference)
//
#include <hip/hip_runtime.h>
#include <math.h>

#define Bsz 16384
#define Msz 512
#define Nsz 2048

typedef _Float16 half8 __attribute__((ext_vector_type(8)));
typedef _Float16 half4 __attribute__((ext_vector_type(4)));
typedef _Float16 half2v __attribute__((ext_vector_type(2)));
typedef float floatx16 __attribute__((ext_vector_type(16)));
typedef unsigned int uint;

struct HL { _Float16 h, l; };
__device__ __forceinline__ HL split1(float x) {
    HL r;
    r.h = (_Float16)x;
    r.l = (_Float16)(x - (float)r.h);   // exact residual (two-term split)
    return r;
}
__device__ __forceinline__ uint packHL(float x) {
    HL s = split1(x);
    return (uint)__builtin_bit_cast(unsigned short, s.h)
         | ((uint)__builtin_bit_cast(unsigned short, s.l) << 16);
}
__device__ __forceinline__ float unpackHL(uint w) {
    half2v p = __builtin_bit_cast(half2v, w);
    return (float)p.x + (float)p.y;
}

// async global->LDS, 16B per lane. LDS dest = wave-uniform base + lane*16.
__device__ __forceinline__ void gl_lds16(const _Float16* g, _Float16* l) {
    __builtin_amdgcn_global_load_lds(
        (const __attribute__((address_space(1))) unsigned int*)g,
        (__attribute__((address_space(3))) unsigned int*)l, 16, 0, 0);
}

// fragment-permuted layout (32x32x16 MFMA), lane-linear (bank-conflict-free):
// element (r,k) of [R][K] at frag(r>>5, k>>4)*512
//                          + ((k>>3)&1)*256 + (r&31)*8 + (k&7)      [halves]
// => lane l's half8 operand (r=l&31, k=(l>>5)*8 ..+7) sits at frag*512 + l*8,
//    so a wave's ds_read_b128 covers 1KB contiguous: all 32 banks per phase.

// zero 19*Bsz floats (t2 slabs 1..9 + na2 slabs 0..9, contiguous)
__global__ __launch_bounds__(256) void zero_kernel(float4* __restrict__ p) {
    p[blockIdx.x * 256 + threadIdx.x] = make_float4(0.f, 0.f, 0.f, 0.f);
}

// iter-0: v = batch -> single f16 permuted plane; t2s[0][b] = sum(v^2) (fp32).
__global__ __launch_bounds__(256) void init_kernel(const float* __restrict__ batch,
        _Float16* __restrict__ vh, float* __restrict__ t2) {
    const int wave = threadIdx.x >> 6;
    const int lane = threadIdx.x & 63;
    const int b = (blockIdx.x << 2) + wave;
    const float* row = batch + (size_t)b * Msz + lane * 8;
    float4 a = *(const float4*)row;
    float4 c = *(const float4*)(row + 4);
    half8 h;
    h[0] = (_Float16)a.x; h[1] = (_Float16)a.y;
    h[2] = (_Float16)a.z; h[3] = (_Float16)a.w;
    h[4] = (_Float16)c.x; h[5] = (_Float16)c.y;
    h[6] = (_Float16)c.z; h[7] = (_Float16)c.w;
    // m = lane*8: frag col = lane>>1, (k>>3)&1 = lane&1, k&7 = 0
    const size_t off = ((size_t)(b >> 5) * 32 + (lane >> 1)) * 512
                     + ((size_t)(lane & 1) << 8) + ((b & 31) << 3);
    *(half8*)(vh + off) = h;
    float s = a.x*a.x + a.y*a.y + a.z*a.z + a.w*a.w
            + c.x*c.x + c.y*c.y + c.z*c.z + c.w*c.w;
#pragma unroll
    for (int off2 = 32; off2 > 0; off2 >>= 1) s += __shfl_down(s, off2);
    if (lane == 0) t2[b] = s;
}

// One-time: D [M][N] fp32 -> Dperm hi/lo  (gemm2 B: r=m, k=n, K=2048)
//                        and Dtperm hi/lo (gemm1 B: r=n, k=m, K=512)
__global__ __launch_bounds__(256) void convD_kernel(const float* __restrict__ D,
        _Float16* __restrict__ Dph, _Float16* __restrict__ Dpl,
        _Float16* __restrict__ Dtph, _Float16* __restrict__ Dtpl) {
    __shared__ float T[64][65];
    const int t = threadIdx.x;
    const int tx = t & 15, ty = t >> 4;
    const int n0 = blockIdx.x << 6, m0 = blockIdx.y << 6;
#pragma unroll
    for (int q = 0; q < 4; ++q) {
        const int mr = m0 + (ty << 2) + q;
        const int nc = n0 + (tx << 2);
        float4 d = *(const float4*)(D + (size_t)mr * Nsz + nc);
        half4 h, l;
        HL s0 = split1(d.x), s1 = split1(d.y), s2 = split1(d.z), s3 = split1(d.w);
        h[0] = s0.h; l[0] = s0.l; h[1] = s1.h; l[1] = s1.l;
        h[2] = s2.h; l[2] = s2.l; h[3] = s3.h; l[3] = s3.l;
        // r=mr, k=nc (nc multiple of 4 -> 4 halves contiguous in k&7 group)
        const size_t o2 = ((size_t)(mr >> 5) * 128 + (nc >> 4)) * 512
                        + (((size_t)(nc >> 3) & 1) << 8) + ((mr & 31) << 3) + (nc & 7);
        *(half4*)(Dph + o2) = h;
        *(half4*)(Dpl + o2) = l;
        T[(tx << 2) + 0][(ty << 2) + q] = d.x;
        T[(tx << 2) + 1][(ty << 2) + q] = d.y;
        T[(tx << 2) + 2][(ty << 2) + q] = d.z;
        T[(tx << 2) + 3][(ty << 2) + q] = d.w;
    }
    __syncthreads();
#pragma unroll
    for (int q = 0; q < 4; ++q) {
        const int nr = n0 + (ty << 2) + q;
        const int mc = m0 + (tx << 2);
        float4 d = make_float4(T[(ty << 2) + q][tx << 2],
                               T[(ty << 2) + q][(tx << 2) + 1],
                               T[(ty << 2) + q][(tx << 2) + 2],
                               T[(ty << 2) + q][(tx << 2) + 3]);
        half4 h, l;
        HL s0 = split1(d.x), s1 = split1(d.y), s2 = split1(d.z), s3 = split1(d.w);
        h[0] = s0.h; l[0] = s0.l; h[1] = s1.h; l[1] = s1.l;
        h[2] = s2.h; l[2] = s2.l; h[3] = s3.h; l[3] = s3.l;
        // r=nr, k=mc
        const size_t o1 = ((size_t)(nr >> 5) * 32 + (mc >> 4)) * 512
                        + (((size_t)(mc >> 3) & 1) << 8) + ((nr & 31) << 3) + (mc & 7);
        *(half4*)(Dtph + o1) = h;
        *(half4*)(Dtpl + o1) = l;
    }
}

// gemm1: alpha = relu((first?0:alpha) + beta*(v@D) - t[b]); fused na2 atomic.
// 2-term split: A = v single f16 plane; B = Dt hi/lo. Double-buffered LDS (48KB),
// 2-phase pipeline: STAGE(c+1) issued before compute(c), one drain+barrier/chunk.
__global__ __launch_bounds__(256, 3) void gemm1_kernel(
        const _Float16* __restrict__ Av,
        const _Float16* __restrict__ Bth, const _Float16* __restrict__ Btl,
        const float* __restrict__ t2,
        uint* __restrict__ alphaP,
        float* __restrict__ na2,
        const float* __restrict__ beta_p, const float* __restrict__ gamma_p,
        int first, int last) {
    __shared__ _Float16 lds[24576];   // 48KB: 2 x (A | Bh | Bl), 4096 halves each

    const int tid = threadIdx.x;
    const int wave = tid >> 6, lane = tid & 63;
    const int wy = wave >> 1, wx = wave & 1;
    const int ln = lane & 31, lh = lane >> 5;
    const int bid = blockIdx.x;
    const int b0 = (bid & 127) << 7;    // row-tile sharers (stride-128 bids) -> same XCD
    const int n0 = (bid >> 7) << 7;
    const int R0 = b0 >> 5, C0 = n0 >> 5;

    floatx16 acc[2][2] = {};

    // staging: wave0 -> A plane, wave1 -> Bh, wave2 -> Bl, wave3 idle
    const _Float16* gsrc =
        (wave == 0) ? Av + (size_t)R0 * 32 * 512 :
        (wave == 1) ? Bth + (size_t)C0 * 32 * 512 :
                      Btl + (size_t)C0 * 32 * 512;
    gsrc += lane * 8;                    // 16B per lane

    const int ro = lane << 3;            // lane-linear fragment read offset (halves)

    auto stage = [&](int c, int d) {
        if (wave < 3) {
            _Float16* lp = lds + d * 12288 + wave * 4096;
#pragma unroll
            for (int f = 0; f < 8; ++f) {    // frag (rtile i = f>>1, ktile j = f&1)
                const int i = f >> 1, j = f & 1;
                gl_lds16(gsrc + (((size_t)i * 32 + 2 * c + j) << 9), lp + (f << 9));
            }
        }
    };

    stage(0, 0);
    __builtin_amdgcn_s_waitcnt(0);
    __syncthreads();

    for (int c = 0; c < 16; ++c) {
        const int cur = c & 1;
        if (c < 15) stage(c + 1, cur ^ 1);   // in flight under compute(c)
        const _Float16* lb = lds + cur * 12288;
#pragma unroll
        for (int ks = 0; ks < 2; ++ks) {
            half8 fa[2], fbh[2], fbl[2];
#pragma unroll
            for (int i = 0; i < 2; ++i) {
                const int sa = (((wy * 2 + i) << 1) + ks) << 9;
                const int sb = (((wx * 2 + i) << 1) + ks) << 9;
                fa[i]  = *(const half8*)(lb + sa + ro);
                fbh[i] = *(const half8*)(lb + 4096 + sb + ro);
                fbl[i] = *(const half8*)(lb + 8192 + sb + ro);
            }
#pragma unroll
            for (int j = 0; j < 2; ++j)
#pragma unroll
                for (int i = 0; i < 2; ++i) {
                    acc[i][j] = __builtin_amdgcn_mfma_f32_32x32x16_f16(fa[i], fbh[j], acc[i][j], 0, 0, 0);
                    acc[i][j] = __builtin_amdgcn_mfma_f32_32x32x16_f16(fa[i], fbl[j], acc[i][j], 0, 0, 0);
                }
        }
        __builtin_amdgcn_s_waitcnt(0);   // drain this chunk's prefetch DMA
        __syncthreads();
    }

    const float beta = beta_p[0];
    const float tc = gamma_p[0] * 0.044194173824159216f;   // gamma / sqrt(512)
#pragma unroll
    for (int i = 0; i < 2; ++i) {
#pragma unroll
        for (int reg = 0; reg < 16; ++reg) {
            const int rr = (reg & 3) + 8 * (reg >> 2) + 4 * lh;   // 0..31
            const int b = b0 + wy * 64 + i * 32 + rr;
            const float tb = tc * sqrtf(t2[b]);
            uint* arow = alphaP + (size_t)b * Nsz + n0 + wx * 64 + ln;
            float s = 0.f;
#pragma unroll
            for (int j = 0; j < 2; ++j) {
                float z = first ? 0.f : unpackHL(arow[j * 32]);
                float val = fmaxf(fmaf(beta, acc[i][j][reg], z) - tb, 0.f);
                if (last) ((float*)arow)[j * 32] = val;   // final fp32, same 4-B slot
                else      arow[j * 32] = packHL(val);
                s = fmaf(val, val, s);
            }
            s += __shfl_down(s, 16, 32);
            s += __shfl_down(s, 8, 32);
            s += __shfl_down(s, 4, 32);
            s += __shfl_down(s, 2, 32);
            s += __shfl_down(s, 1, 32);
            if (ln == 0) atomicAdd(&na2[b], s);
        }
    }
}

// gemm2: v = y - beta*(alpha@D^T) + beta/512*sqrt(na2[b])*v_old; fused t2 atomic.
// 2-term split: A = alpha_hi (extracted from packed, ds_write in frag format);
// B = D hi/lo via global_load_lds. Double-buffered LDS (48KB), 2-phase pipeline.
__global__ __launch_bounds__(256, 2) void gemm2_kernel(
        const uint* __restrict__ alphaP,
        const _Float16* __restrict__ Bh, const _Float16* __restrict__ Bl,
        const float* __restrict__ na2,
        const float* __restrict__ y,
        _Float16* __restrict__ vh,
        float* __restrict__ t2,
        const float* __restrict__ beta_p) {
    __shared__ _Float16 lds[24576];   // 2 x (A | Bh | Bl), 4096 halves each

    const int tid = threadIdx.x;
    const int wave = tid >> 6, lane = tid & 63;
    const int wy = wave >> 1, wx = wave & 1;
    const int ln = lane & 31, lh = lane >> 5;
    const int bid = blockIdx.x;
    const int b0 = (bid & 127) << 7;
    const int m0 = (bid >> 7) << 7;
    const int C0 = m0 >> 5;

    floatx16 acc[2][2] = {};

    // A staging: thread (srow, skq) covers one ktile-half of one row (16 words)
    const int srow = tid >> 1;
    const int skq  = (tid & 1) << 4;
    const uint* apP = alphaP + (size_t)(b0 + srow) * Nsz + skq;
    // lane-linear frag layout: k&15 in 0..7 -> +0, 8..15 -> +256
    const int awo = ((((srow >> 5) << 1) + (skq >> 4)) << 9) + ((srow & 31) << 3);

    // B staging via gl_lds: wave0 -> Bh plane, wave1 -> Bl plane
    const _Float16* gB = ((wave & 1) ? Bl : Bh) + (size_t)C0 * 128 * 512 + lane * 8;

    const int ro = lane << 3;

    uint4 a0, a1, a2, a3;
    auto loadA = [&](int c) {
        const uint* nx = apP + c * 32;
        a0 = *(const uint4*)(nx);
        a1 = *(const uint4*)(nx + 4);
        a2 = *(const uint4*)(nx + 8);
        a3 = *(const uint4*)(nx + 12);
    };
    auto writeA = [&](int d) {      // extract hi (low16s) and ds_write in frag format
        uint4 ha, hb;
        ha.x = __builtin_amdgcn_perm(a0.y, a0.x, 0x05040100u);
        ha.y = __builtin_amdgcn_perm(a0.w, a0.z, 0x05040100u);
        ha.z = __builtin_amdgcn_perm(a1.y, a1.x, 0x05040100u);
        ha.w = __builtin_amdgcn_perm(a1.w, a1.z, 0x05040100u);
        hb.x = __builtin_amdgcn_perm(a2.y, a2.x, 0x05040100u);
        hb.y = __builtin_amdgcn_perm(a2.w, a2.z, 0x05040100u);
        hb.z = __builtin_amdgcn_perm(a3.y, a3.x, 0x05040100u);
        hb.w = __builtin_amdgcn_perm(a3.w, a3.z, 0x05040100u);
        _Float16* aw = lds + d * 12288 + awo;
        *(uint4*)aw = ha;
        *(uint4*)(aw + 256) = hb;
    };
    auto stageB = [&](int c, int d) {
        if (wave < 2) {
            _Float16* lB = lds + d * 12288 + 4096 + (wave & 1) * 4096;
#pragma unroll
            for (int f = 0; f < 8; ++f) {
                const int i = f >> 1, j = f & 1;
                gl_lds16(gB + (((size_t)i * 128 + 2 * c + j) << 9), lB + (f << 9));
            }
        }
    };

    loadA(0);
    writeA(0);
    stageB(0, 0);
    loadA(1);                        // regs hold A(1) entering iter 0
    __builtin_amdgcn_s_waitcnt(0);
    __syncthreads();

    for (int c = 0; c < 64; ++c) {
        const int cur = c & 1;
        if (c < 63) {
            writeA(cur ^ 1);         // A(c+1) from regs (loaded last iter)
            stageB(c + 1, cur ^ 1);
            if (c < 62) loadA(c + 2);
        }
        const _Float16* lb = lds + cur * 12288;
#pragma unroll
        for (int ks = 0; ks < 2; ++ks) {
            half8 fa[2], fbh[2], fbl[2];
#pragma unroll
            for (int i = 0; i < 2; ++i) {
                const int sa = (((wy * 2 + i) << 1) + ks) << 9;
                const int sb = (((wx * 2 + i) << 1) + ks) << 9;
                fa[i]  = *(const half8*)(lb + sa + ro);
                fbh[i] = *(const half8*)(lb + 4096 + sb + ro);
                fbl[i] = *(const half8*)(lb + 8192 + sb + ro);
            }
#pragma unroll
            for (int j = 0; j < 2; ++j)
#pragma unroll
                for (int i = 0; i < 2; ++i) {
                    acc[i][j] = __builtin_amdgcn_mfma_f32_32x32x16_f16(fa[i], fbh[j], acc[i][j], 0, 0, 0);
                    acc[i][j] = __builtin_amdgcn_mfma_f32_32x32x16_f16(fa[i], fbl[j], acc[i][j], 0, 0, 0);
                }
        }
        __builtin_amdgcn_s_waitcnt(0);
        __syncthreads();
    }

    const float beta = beta_p[0];
#pragma unroll
    for (int i = 0; i < 2; ++i) {
#pragma unroll
        for (int reg = 0; reg < 16; ++reg) {
            const int rr = (reg & 3) + 8 * (reg >> 2) + 4 * lh;
            const int b = b0 + wy * 64 + i * 32 + rr;
            const float cb = beta * (1.0f / 512.0f) * sqrtf(na2[b]);
            float s = 0.f;
#pragma unroll
            for (int j = 0; j < 2; ++j) {
                const int m = m0 + wx * 64 + j * 32 + ln;
                const size_t po = ((size_t)(b >> 5) * 32 + (m >> 4)) * 512
                                + (((size_t)(m >> 3) & 1) << 8) + ((b & 31) << 3) + (m & 7);
                const size_t yi = (size_t)b * Msz + m;
                float vold = (float)vh[po];
                float val = y[yi] - beta * acc[i][j][reg] + cb * vold;
                vh[po] = (_Float16)val;
                s = fmaf(val, val, s);
            }
            s += __shfl_down(s, 16, 32);
            s += __shfl_down(s, 8, 32);
            s += __shfl_down(s, 4, 32);
            s += __shfl_down(s, 2, 32);
            s += __shfl_down(s, 1, 32);
            if (ln == 0) atomicAdd(&t2[b], s);
        }
    }
}

extern "C" void kernel_launch(void* const* d_in, const int* in_sizes, int n_in,
                              void* d_out, int out_size, void* d_ws, size_t ws_size,
                              hipStream_t stream) {
    (void)in_sizes; (void)n_in; (void)out_size; (void)ws_size;
    const float* batch   = (const float*)d_in[0];   // [B, M]
    const float* D       = (const float*)d_in[1];   // [M, N]
    const float* gamma_p = (const float*)d_in[2];   // scalar
    const float* beta_p  = (const float*)d_in[3];   // scalar

    uint* alphaP = (uint*)d_out;    // packed hi/lo per element (plain layout); fp32 after final iter

    // workspace (~27 MB)
    _Float16* vh   = (_Float16*)d_ws;               // [B*M] permuted, single plane
    _Float16* Dph  = vh + (size_t)Bsz * Msz;        // [M*N] permuted (gemm2 B)
    _Float16* Dpl  = Dph + (size_t)Msz * Nsz;
    _Float16* Dtph = Dpl + (size_t)Msz * Nsz;       // [N*M] permuted (gemm1 B)
    _Float16* Dtpl = Dtph + (size_t)Msz * Nsz;
    float*    t2s  = (float*)(Dtpl + (size_t)Msz * Nsz);   // [10][Bsz] sum v^2
    float*    na2s = t2s + 10 * Bsz;                        // [10][Bsz] sum alpha^2

    // zero t2 slabs 1..9 + na2 slabs 0..9 (contiguous 19*Bsz floats)
    zero_kernel<<<19 * Bsz / 1024, 256, 0, stream>>>((float4*)(t2s + Bsz));
    convD_kernel<<<dim3(Nsz / 64, Msz / 64), 256, 0, stream>>>(D, Dph, Dpl, Dtph, Dtpl);
    init_kernel<<<Bsz / 4, 256, 0, stream>>>(batch, vh, t2s);   // writes t2 slab 0

    for (int it = 0; it < 10; ++it) {
        gemm1_kernel<<<2048, 256, 0, stream>>>(vh, Dtph, Dtpl,
                                               t2s + (size_t)it * Bsz,
                                               alphaP,
                                               na2s + (size_t)it * Bsz,
                                               beta_p, gamma_p,
                                               it == 0 ? 1 : 0, it == 9 ? 1 : 0);
        if (it < 9) {   // last iteration's new_v is unused by the reference output
            gemm2_kernel<<<512, 256, 0, stream>>>(alphaP, Dph, Dpl,
                                                  na2s + (size_t)it * Bsz,
                                                  batch, vh,
                                                  t2s + (size_t)(it + 1) * Bsz,
                                                  beta_p);
        }
    }
}

// Round 2
// 2330.476 us; speedup vs baseline: 1.0799x; 1.0799x over previous
//
#include <hip/hip_runtime.h>
#include <math.h>

#define Bsz 16384
#define Msz 512
#define Nsz 2048

typedef _Float16 half8 __attribute__((ext_vector_type(8)));
typedef _Float16 half4 __attribute__((ext_vector_type(4)));
typedef _Float16 half2v __attribute__((ext_vector_type(2)));
typedef float floatx16 __attribute__((ext_vector_type(16)));
typedef unsigned int uint;

struct HL { _Float16 h, l; };
__device__ __forceinline__ HL split1(float x) {
    HL r;
    r.h = (_Float16)x;
    r.l = (_Float16)(x - (float)r.h);   // exact residual (two-term split)
    return r;
}
__device__ __forceinline__ uint packHL(float x) {
    HL s = split1(x);
    return (uint)__builtin_bit_cast(unsigned short, s.h)
         | ((uint)__builtin_bit_cast(unsigned short, s.l) << 16);
}
__device__ __forceinline__ float unpackHL(uint w) {
    half2v p = __builtin_bit_cast(half2v, w);
    return (float)p.x + (float)p.y;
}

// async global->LDS, 16B per lane. LDS dest = wave-uniform base + lane*16.
__device__ __forceinline__ void gl_lds16(const _Float16* g, _Float16* l) {
    __builtin_amdgcn_global_load_lds(
        (const __attribute__((address_space(1))) unsigned int*)g,
        (__attribute__((address_space(3))) unsigned int*)l, 16, 0, 0);
}

// fragment-permuted layout (32x32x16 MFMA), lane-linear (bank-conflict-free):
// element (r,k) of [R][K] at frag(r>>5, k>>4)*512
//                          + ((k>>3)&1)*256 + (r&31)*8 + (k&7)      [halves]
// => lane l's half8 operand (r=l&31, k=(l>>5)*8 ..+7) sits at frag*512 + l*8:
//    a wave's ds_read_b128 covers 1KB contiguous -> all 32 banks, conflict-free.

// zero 19*Bsz floats (t2 slabs 1..9 + na2 slabs 0..9, contiguous)
__global__ __launch_bounds__(256) void zero_kernel(float4* __restrict__ p) {
    p[blockIdx.x * 256 + threadIdx.x] = make_float4(0.f, 0.f, 0.f, 0.f);
}

// iter-0: v = batch -> single f16 permuted plane; t2s[0][b] = sum(v^2) (fp32).
__global__ __launch_bounds__(256) void init_kernel(const float* __restrict__ batch,
        _Float16* __restrict__ vh, float* __restrict__ t2) {
    const int wave = threadIdx.x >> 6;
    const int lane = threadIdx.x & 63;
    const int b = (blockIdx.x << 2) + wave;
    const float* row = batch + (size_t)b * Msz + lane * 8;
    float4 a = *(const float4*)row;
    float4 c = *(const float4*)(row + 4);
    half8 h;
    h[0] = (_Float16)a.x; h[1] = (_Float16)a.y;
    h[2] = (_Float16)a.z; h[3] = (_Float16)a.w;
    h[4] = (_Float16)c.x; h[5] = (_Float16)c.y;
    h[6] = (_Float16)c.z; h[7] = (_Float16)c.w;
    // m = lane*8: frag col = lane>>1, (k>>3)&1 = lane&1, k&7 = 0
    const size_t off = ((size_t)(b >> 5) * 32 + (lane >> 1)) * 512
                     + ((size_t)(lane & 1) << 8) + ((b & 31) << 3);
    *(half8*)(vh + off) = h;
    float s = a.x*a.x + a.y*a.y + a.z*a.z + a.w*a.w
            + c.x*c.x + c.y*c.y + c.z*c.z + c.w*c.w;
#pragma unroll
    for (int off2 = 32; off2 > 0; off2 >>= 1) s += __shfl_down(s, off2);
    if (lane == 0) t2[b] = s;
}

// One-time: D [M][N] fp32 -> Dperm hi/lo  (gemm2 B: r=m, k=n, K=2048)
//                        and Dtperm hi/lo (gemm1 B: r=n, k=m, K=512)
__global__ __launch_bounds__(256) void convD_kernel(const float* __restrict__ D,
        _Float16* __restrict__ Dph, _Float16* __restrict__ Dpl,
        _Float16* __restrict__ Dtph, _Float16* __restrict__ Dtpl) {
    __shared__ float T[64][65];
    const int t = threadIdx.x;
    const int tx = t & 15, ty = t >> 4;
    const int n0 = blockIdx.x << 6, m0 = blockIdx.y << 6;
#pragma unroll
    for (int q = 0; q < 4; ++q) {
        const int mr = m0 + (ty << 2) + q;
        const int nc = n0 + (tx << 2);
        float4 d = *(const float4*)(D + (size_t)mr * Nsz + nc);
        half4 h, l;
        HL s0 = split1(d.x), s1 = split1(d.y), s2 = split1(d.z), s3 = split1(d.w);
        h[0] = s0.h; l[0] = s0.l; h[1] = s1.h; l[1] = s1.l;
        h[2] = s2.h; l[2] = s2.l; h[3] = s3.h; l[3] = s3.l;
        // r=mr, k=nc (nc multiple of 4 -> 4 halves contiguous in k&7 group)
        const size_t o2 = ((size_t)(mr >> 5) * 128 + (nc >> 4)) * 512
                        + (((size_t)(nc >> 3) & 1) << 8) + ((mr & 31) << 3) + (nc & 7);
        *(half4*)(Dph + o2) = h;
        *(half4*)(Dpl + o2) = l;
        T[(tx << 2) + 0][(ty << 2) + q] = d.x;
        T[(tx << 2) + 1][(ty << 2) + q] = d.y;
        T[(tx << 2) + 2][(ty << 2) + q] = d.z;
        T[(tx << 2) + 3][(ty << 2) + q] = d.w;
    }
    __syncthreads();
#pragma unroll
    for (int q = 0; q < 4; ++q) {
        const int nr = n0 + (ty << 2) + q;
        const int mc = m0 + (tx << 2);
        float4 d = make_float4(T[(ty << 2) + q][tx << 2],
                               T[(ty << 2) + q][(tx << 2) + 1],
                               T[(ty << 2) + q][(tx << 2) + 2],
                               T[(ty << 2) + q][(tx << 2) + 3]);
        half4 h, l;
        HL s0 = split1(d.x), s1 = split1(d.y), s2 = split1(d.z), s3 = split1(d.w);
        h[0] = s0.h; l[0] = s0.l; h[1] = s1.h; l[1] = s1.l;
        h[2] = s2.h; l[2] = s2.l; h[3] = s3.h; l[3] = s3.l;
        // r=nr, k=mc
        const size_t o1 = ((size_t)(nr >> 5) * 32 + (mc >> 4)) * 512
                        + (((size_t)(mc >> 3) & 1) << 8) + ((nr & 31) << 3) + (mc & 7);
        *(half4*)(Dtph + o1) = h;
        *(half4*)(Dtpl + o1) = l;
    }
}

// gemm1: alpha = relu((first?0:alpha) + beta*(v@D) - t[b]); fused na2 atomic.
// 256x128 tile, 8 waves (4x2), 32KB single-buffer LDS, R0-proven sync
// (stage -> drain -> compute; cross-block TLP hides the drain), lane-linear
// conflict-free fragment layout. Staging-BW need: 128 B/cyc/CU (was 192).
__global__ __launch_bounds__(512, 4) void gemm1_kernel(
        const _Float16* __restrict__ Av,
        const _Float16* __restrict__ Bth, const _Float16* __restrict__ Btl,
        const float* __restrict__ t2,
        uint* __restrict__ alphaP,
        float* __restrict__ na2,
        const float* __restrict__ beta_p, const float* __restrict__ gamma_p,
        int first, int last) {
    __shared__ _Float16 lds[16384];   // 32KB: A 16 frags | Bh 8 | Bl 8 (512h each)

    const int tid = threadIdx.x;
    const int wave = tid >> 6, lane = tid & 63;
    const int wy = wave >> 1, wx = wave & 1;     // 4x2 wave grid
    const int ln = lane & 31, lh = lane >> 5;
    const int bid = blockIdx.x;
    const int b0 = (bid & 63) << 8;              // 64 row-tiles of 256
    const int n0 = (bid >> 6) << 7;              // 16 col-tiles of 128
    const int R0 = b0 >> 5, C0 = n0 >> 5;

    floatx16 acc[2][2] = {};

    // staging: 32 frags/chunk, 4 per wave.
    // waves 0-3 -> A frags 0..15; waves 4,5 -> Bh frags 16..23; 6,7 -> Bl 24..31
    const _Float16* plane = (wave < 4) ? Av : (wave < 6) ? Bth : Btl;
    const int T0 = (wave < 4) ? R0 : C0;
    const int tb = (wave < 4) ? 2 * wave : ((wave & 1) ? 2 : 0);
    const int f0 = 4 * wave;
    const _Float16* P = plane + ((size_t)(T0 + tb) * 32) * 512 + lane * 8;

    const int ro = lane << 3;            // lane-linear fragment read offset (halves)

    for (int c = 0; c < 16; ++c) {
        __syncthreads();                 // previous chunk's frag reads done
#pragma unroll
        for (int q = 0; q < 4; ++q) {    // q>>1 = tile step, q&1 = ktile
            gl_lds16(P + (size_t)(q >> 1) * (32 * 512) + (((2 * c) + (q & 1)) << 9),
                     lds + ((f0 + q) << 9));
        }
        __builtin_amdgcn_s_waitcnt(0);   // drain this wave's DMA
        __syncthreads();                 // all frags staged

#pragma unroll
        for (int ks = 0; ks < 2; ++ks) {
            half8 fa[2], fbh[2], fbl[2];
#pragma unroll
            for (int i = 0; i < 2; ++i) {
                const int sa = (((wy * 2 + i) << 1) + ks) << 9;
                const int sb = (((wx * 2 + i) << 1) + ks) << 9;
                fa[i]  = *(const half8*)(lds + sa + ro);
                fbh[i] = *(const half8*)(lds + 8192 + sb + ro);
                fbl[i] = *(const half8*)(lds + 12288 + sb + ro);
            }
#pragma unroll
            for (int j = 0; j < 2; ++j)
#pragma unroll
                for (int i = 0; i < 2; ++i) {
                    acc[i][j] = __builtin_amdgcn_mfma_f32_32x32x16_f16(fa[i], fbh[j], acc[i][j], 0, 0, 0);
                    acc[i][j] = __builtin_amdgcn_mfma_f32_32x32x16_f16(fa[i], fbl[j], acc[i][j], 0, 0, 0);
                }
        }
    }

    const float beta = beta_p[0];
    const float tc = gamma_p[0] * 0.044194173824159216f;   // gamma / sqrt(512)
#pragma unroll
    for (int i = 0; i < 2; ++i) {
#pragma unroll
        for (int reg = 0; reg < 16; ++reg) {
            const int rr = (reg & 3) + 8 * (reg >> 2) + 4 * lh;   // 0..31
            const int b = b0 + wy * 64 + i * 32 + rr;
            const float tb2 = tc * sqrtf(t2[b]);
            uint* arow = alphaP + (size_t)b * Nsz + n0 + wx * 64 + ln;
            float s = 0.f;
#pragma unroll
            for (int j = 0; j < 2; ++j) {
                float z = first ? 0.f : unpackHL(arow[j * 32]);
                float val = fmaxf(fmaf(beta, acc[i][j][reg], z) - tb2, 0.f);
                if (last) ((float*)arow)[j * 32] = val;   // final fp32, same 4-B slot
                else      arow[j * 32] = packHL(val);
                s = fmaf(val, val, s);
            }
            s += __shfl_down(s, 16, 32);
            s += __shfl_down(s, 8, 32);
            s += __shfl_down(s, 4, 32);
            s += __shfl_down(s, 2, 32);
            s += __shfl_down(s, 1, 32);
            if (ln == 0) atomicAdd(&na2[b], s);
        }
    }
}

// gemm2: v = y - beta*(alpha@D^T) + beta/512*sqrt(na2[b])*v_old; fused t2 atomic.
// 256x128 tile, 8 waves, 32KB single-buffer. A = alpha_hi extracted in regs
// (prefetched one chunk ahead) + ds_write; B = D hi/lo via gl_lds (2 frags/wave).
__global__ __launch_bounds__(512, 2) void gemm2_kernel(
        const uint* __restrict__ alphaP,
        const _Float16* __restrict__ Bh, const _Float16* __restrict__ Bl,
        const float* __restrict__ na2,
        const float* __restrict__ y,
        _Float16* __restrict__ vh,
        float* __restrict__ t2,
        const float* __restrict__ beta_p) {
    __shared__ _Float16 lds[16384];   // A 16 frags | Bh 8 | Bl 8

    const int tid = threadIdx.x;
    const int wave = tid >> 6, lane = tid & 63;
    const int wy = wave >> 1, wx = wave & 1;
    const int ln = lane & 31, lh = lane >> 5;
    const int bid = blockIdx.x;
    const int b0 = (bid & 63) << 8;              // 64 row-tiles of 256
    const int m0 = (bid >> 6) << 7;              // 4 col-tiles of 128
    const int C0 = m0 >> 5;

    floatx16 acc[2][2] = {};

    // A staging: thread (srow, skq) covers one ktile-half of one row (16 words)
    const int srow = tid >> 1;                   // 0..255
    const int skq  = (tid & 1) << 4;
    const uint* apP = alphaP + (size_t)(b0 + srow) * Nsz + skq;
    // lane-linear frag layout: k&15 in 0..7 -> +0, 8..15 -> +256
    const int awo = ((((srow >> 5) << 1) + (skq >> 4)) << 9) + ((srow & 31) << 3);

    // B staging via gl_lds: waves 0-3 -> Bh ctile (wave&3); waves 4-7 -> Bl
    const _Float16* gB = ((wave < 4) ? Bh : Bl)
                       + ((size_t)(C0 + (wave & 3)) * 128) * 512 + lane * 8;
    const int fB = 16 + ((wave < 4) ? 0 : 8) + (wave & 3) * 2;

    const int ro = lane << 3;

    uint4 a0, a1, a2, a3;
    auto loadA = [&](int c) {
        const uint* nx = apP + c * 32;
        a0 = *(const uint4*)(nx);
        a1 = *(const uint4*)(nx + 4);
        a2 = *(const uint4*)(nx + 8);
        a3 = *(const uint4*)(nx + 12);
    };
    auto writeA = [&]() {      // extract hi (low16s) and ds_write in frag format
        uint4 ha, hb;
        ha.x = __builtin_amdgcn_perm(a0.y, a0.x, 0x05040100u);
        ha.y = __builtin_amdgcn_perm(a0.w, a0.z, 0x05040100u);
        ha.z = __builtin_amdgcn_perm(a1.y, a1.x, 0x05040100u);
        ha.w = __builtin_amdgcn_perm(a1.w, a1.z, 0x05040100u);
        hb.x = __builtin_amdgcn_perm(a2.y, a2.x, 0x05040100u);
        hb.y = __builtin_amdgcn_perm(a2.w, a2.z, 0x05040100u);
        hb.z = __builtin_amdgcn_perm(a3.y, a3.x, 0x05040100u);
        hb.w = __builtin_amdgcn_perm(a3.w, a3.z, 0x05040100u);
        _Float16* aw = lds + awo;
        *(uint4*)aw = ha;
        *(uint4*)(aw + 256) = hb;
    };

    loadA(0);

    for (int c = 0; c < 64; ++c) {
        __syncthreads();                 // previous chunk's frag reads done
        writeA();                        // A(c) from regs
#pragma unroll
        for (int kt = 0; kt < 2; ++kt)
            gl_lds16(gB + (((size_t)2 * c + kt) << 9), lds + ((fB + kt) << 9));
        if (c < 63) loadA(c + 1);        // overlaps the B-DMA latency
        __builtin_amdgcn_s_waitcnt(0);
        __syncthreads();

#pragma unroll
        for (int ks = 0; ks < 2; ++ks) {
            half8 fa[2], fbh[2], fbl[2];
#pragma unroll
            for (int i = 0; i < 2; ++i) {
                const int sa = (((wy * 2 + i) << 1) + ks) << 9;
                const int sb = (((wx * 2 + i) << 1) + ks) << 9;
                fa[i]  = *(const half8*)(lds + sa + ro);
                fbh[i] = *(const half8*)(lds + 8192 + sb + ro);
                fbl[i] = *(const half8*)(lds + 12288 + sb + ro);
            }
#pragma unroll
            for (int j = 0; j < 2; ++j)
#pragma unroll
                for (int i = 0; i < 2; ++i) {
                    acc[i][j] = __builtin_amdgcn_mfma_f32_32x32x16_f16(fa[i], fbh[j], acc[i][j], 0, 0, 0);
                    acc[i][j] = __builtin_amdgcn_mfma_f32_32x32x16_f16(fa[i], fbl[j], acc[i][j], 0, 0, 0);
                }
        }
    }

    const float beta = beta_p[0];
#pragma unroll
    for (int i = 0; i < 2; ++i) {
#pragma unroll
        for (int reg = 0; reg < 16; ++reg) {
            const int rr = (reg & 3) + 8 * (reg >> 2) + 4 * lh;
            const int b = b0 + wy * 64 + i * 32 + rr;
            const float cb = beta * (1.0f / 512.0f) * sqrtf(na2[b]);
            float s = 0.f;
#pragma unroll
            for (int j = 0; j < 2; ++j) {
                const int m = m0 + wx * 64 + j * 32 + ln;
                const size_t po = ((size_t)(b >> 5) * 32 + (m >> 4)) * 512
                                + (((size_t)(m >> 3) & 1) << 8) + ((b & 31) << 3) + (m & 7);
                const size_t yi = (size_t)b * Msz + m;
                float vold = (float)vh[po];
                float val = y[yi] - beta * acc[i][j][reg] + cb * vold;
                vh[po] = (_Float16)val;
                s = fmaf(val, val, s);
            }
            s += __shfl_down(s, 16, 32);
            s += __shfl_down(s, 8, 32);
            s += __shfl_down(s, 4, 32);
            s += __shfl_down(s, 2, 32);
            s += __shfl_down(s, 1, 32);
            if (ln == 0) atomicAdd(&t2[b], s);
        }
    }
}

extern "C" void kernel_launch(void* const* d_in, const int* in_sizes, int n_in,
                              void* d_out, int out_size, void* d_ws, size_t ws_size,
                              hipStream_t stream) {
    (void)in_sizes; (void)n_in; (void)out_size; (void)ws_size;
    const float* batch   = (const float*)d_in[0];   // [B, M]
    const float* D       = (const float*)d_in[1];   // [M, N]
    const float* gamma_p = (const float*)d_in[2];   // scalar
    const float* beta_p  = (const float*)d_in[3];   // scalar

    uint* alphaP = (uint*)d_out;    // packed hi/lo per element (plain layout); fp32 after final iter

    // workspace (~27 MB)
    _Float16* vh   = (_Float16*)d_ws;               // [B*M] permuted, single plane
    _Float16* Dph  = vh + (size_t)Bsz * Msz;        // [M*N] permuted (gemm2 B)
    _Float16* Dpl  = Dph + (size_t)Msz * Nsz;
    _Float16* Dtph = Dpl + (size_t)Msz * Nsz;       // [N*M] permuted (gemm1 B)
    _Float16* Dtpl = Dtph + (size_t)Msz * Nsz;
    float*    t2s  = (float*)(Dtpl + (size_t)Msz * Nsz);   // [10][Bsz] sum v^2
    float*    na2s = t2s + 10 * Bsz;                        // [10][Bsz] sum alpha^2

    // zero t2 slabs 1..9 + na2 slabs 0..9 (contiguous 19*Bsz floats)
    zero_kernel<<<19 * Bsz / 1024, 256, 0, stream>>>((float4*)(t2s + Bsz));
    convD_kernel<<<dim3(Nsz / 64, Msz / 64), 256, 0, stream>>>(D, Dph, Dpl, Dtph, Dtpl);
    init_kernel<<<Bsz / 4, 256, 0, stream>>>(batch, vh, t2s);   // writes t2 slab 0

    for (int it = 0; it < 10; ++it) {
        gemm1_kernel<<<1024, 512, 0, stream>>>(vh, Dtph, Dtpl,
                                               t2s + (size_t)it * Bsz,
                                               alphaP,
                                               na2s + (size_t)it * Bsz,
                                               beta_p, gamma_p,
                                               it == 0 ? 1 : 0, it == 9 ? 1 : 0);
        if (it < 9) {   // last iteration's new_v is unused by the reference output
            gemm2_kernel<<<256, 512, 0, stream>>>(alphaP, Dph, Dpl,
                                                  na2s + (size_t)it * Bsz,
                                                  batch, vh,
                                                  t2s + (size_t)(it + 1) * Bsz,
                                                  beta_p);
        }
    }
}

// Round 3
// 2243.327 us; speedup vs baseline: 1.1218x; 1.0388x over previous
//
#include <hip/hip_runtime.h>
#include <math.h>

#define Bsz 16384
#define Msz 512
#define Nsz 2048

typedef _Float16 half8 __attribute__((ext_vector_type(8)));
typedef _Float16 half4 __attribute__((ext_vector_type(4)));
typedef _Float16 half2v __attribute__((ext_vector_type(2)));
typedef float floatx16 __attribute__((ext_vector_type(16)));
typedef unsigned int uint;

struct HL { _Float16 h, l; };
__device__ __forceinline__ HL split1(float x) {
    HL r;
    r.h = (_Float16)x;
    r.l = (_Float16)(x - (float)r.h);   // exact residual (two-term split)
    return r;
}
__device__ __forceinline__ uint packHL(float x) {
    HL s = split1(x);
    return (uint)__builtin_bit_cast(unsigned short, s.h)
         | ((uint)__builtin_bit_cast(unsigned short, s.l) << 16);
}
__device__ __forceinline__ float unpackHL(uint w) {
    half2v p = __builtin_bit_cast(half2v, w);
    return (float)p.x + (float)p.y;
}

// async global->LDS, 16B per lane. LDS dest = wave-uniform base + lane*16.
__device__ __forceinline__ void gl_lds16(const _Float16* g, _Float16* l) {
    __builtin_amdgcn_global_load_lds(
        (const __attribute__((address_space(1))) unsigned int*)g,
        (__attribute__((address_space(3))) unsigned int*)l, 16, 0, 0);
}

// fragment-permuted layout (32x32x16 MFMA), lane-linear (bank-conflict-free):
// element (r,k) of [R][K] at frag(r>>5, k>>4)*512
//                          + ((k>>3)&1)*256 + (r&31)*8 + (k&7)      [halves]
// => lane l's half8 operand (r=l&31, k=(l>>5)*8 ..+7) sits at frag*512 + l*8:
//    a wave's ds_read_b128 covers 1KB contiguous -> all 32 banks, conflict-free.

// zero 19*Bsz floats (t2 slabs 1..9 + na2 slabs 0..9, contiguous)
__global__ __launch_bounds__(256) void zero_kernel(float4* __restrict__ p) {
    p[blockIdx.x * 256 + threadIdx.x] = make_float4(0.f, 0.f, 0.f, 0.f);
}

// iter-0: v = batch -> single f16 permuted plane; t2s[0][b] = sum(v^2) (fp32).
__global__ __launch_bounds__(256) void init_kernel(const float* __restrict__ batch,
        _Float16* __restrict__ vh, float* __restrict__ t2) {
    const int wave = threadIdx.x >> 6;
    const int lane = threadIdx.x & 63;
    const int b = (blockIdx.x << 2) + wave;
    const float* row = batch + (size_t)b * Msz + lane * 8;
    float4 a = *(const float4*)row;
    float4 c = *(const float4*)(row + 4);
    half8 h;
    h[0] = (_Float16)a.x; h[1] = (_Float16)a.y;
    h[2] = (_Float16)a.z; h[3] = (_Float16)a.w;
    h[4] = (_Float16)c.x; h[5] = (_Float16)c.y;
    h[6] = (_Float16)c.z; h[7] = (_Float16)c.w;
    // m = lane*8: frag col = lane>>1, (k>>3)&1 = lane&1, k&7 = 0
    const size_t off = ((size_t)(b >> 5) * 32 + (lane >> 1)) * 512
                     + ((size_t)(lane & 1) << 8) + ((b & 31) << 3);
    *(half8*)(vh + off) = h;
    float s = a.x*a.x + a.y*a.y + a.z*a.z + a.w*a.w
            + c.x*c.x + c.y*c.y + c.z*c.z + c.w*c.w;
#pragma unroll
    for (int off2 = 32; off2 > 0; off2 >>= 1) s += __shfl_down(s, off2);
    if (lane == 0) t2[b] = s;
}

// One-time: D [M][N] fp32 -> Dperm hi/lo  (gemm2 B: r=m, k=n, K=2048)
//                        and Dtperm hi/lo (gemm1 B: r=n, k=m, K=512)
__global__ __launch_bounds__(256) void convD_kernel(const float* __restrict__ D,
        _Float16* __restrict__ Dph, _Float16* __restrict__ Dpl,
        _Float16* __restrict__ Dtph, _Float16* __restrict__ Dtpl) {
    __shared__ float T[64][65];
    const int t = threadIdx.x;
    const int tx = t & 15, ty = t >> 4;
    const int n0 = blockIdx.x << 6, m0 = blockIdx.y << 6;
#pragma unroll
    for (int q = 0; q < 4; ++q) {
        const int mr = m0 + (ty << 2) + q;
        const int nc = n0 + (tx << 2);
        float4 d = *(const float4*)(D + (size_t)mr * Nsz + nc);
        half4 h, l;
        HL s0 = split1(d.x), s1 = split1(d.y), s2 = split1(d.z), s3 = split1(d.w);
        h[0] = s0.h; l[0] = s0.l; h[1] = s1.h; l[1] = s1.l;
        h[2] = s2.h; l[2] = s2.l; h[3] = s3.h; l[3] = s3.l;
        // r=mr, k=nc (nc multiple of 4 -> 4 halves contiguous in k&7 group)
        const size_t o2 = ((size_t)(mr >> 5) * 128 + (nc >> 4)) * 512
                        + (((size_t)(nc >> 3) & 1) << 8) + ((mr & 31) << 3) + (nc & 7);
        *(half4*)(Dph + o2) = h;
        *(half4*)(Dpl + o2) = l;
        T[(tx << 2) + 0][(ty << 2) + q] = d.x;
        T[(tx << 2) + 1][(ty << 2) + q] = d.y;
        T[(tx << 2) + 2][(ty << 2) + q] = d.z;
        T[(tx << 2) + 3][(ty << 2) + q] = d.w;
    }
    __syncthreads();
#pragma unroll
    for (int q = 0; q < 4; ++q) {
        const int nr = n0 + (ty << 2) + q;
        const int mc = m0 + (tx << 2);
        float4 d = make_float4(T[(ty << 2) + q][tx << 2],
                               T[(ty << 2) + q][(tx << 2) + 1],
                               T[(ty << 2) + q][(tx << 2) + 2],
                               T[(ty << 2) + q][(tx << 2) + 3]);
        half4 h, l;
        HL s0 = split1(d.x), s1 = split1(d.y), s2 = split1(d.z), s3 = split1(d.w);
        h[0] = s0.h; l[0] = s0.l; h[1] = s1.h; l[1] = s1.l;
        h[2] = s2.h; l[2] = s2.l; h[3] = s3.h; l[3] = s3.l;
        // r=nr, k=mc
        const size_t o1 = ((size_t)(nr >> 5) * 32 + (mc >> 4)) * 512
                        + (((size_t)(mc >> 3) & 1) << 8) + ((nr & 31) << 3) + (mc & 7);
        *(half4*)(Dtph + o1) = h;
        *(half4*)(Dtpl + o1) = l;
    }
}

// gemm1: alpha = relu((first?0:alpha) + beta*(v@D) - t[b]); fused na2 atomic.
// 256x128 tile, 8 waves (4x2), 32KB single-buffer LDS, stage->drain->compute
// (cross-block TLP hides the drain; ~4 blocks/CU). UNCHANGED from R2 (best).
__global__ __launch_bounds__(512, 4) void gemm1_kernel(
        const _Float16* __restrict__ Av,
        const _Float16* __restrict__ Bth, const _Float16* __restrict__ Btl,
        const float* __restrict__ t2,
        uint* __restrict__ alphaP,
        float* __restrict__ na2,
        const float* __restrict__ beta_p, const float* __restrict__ gamma_p,
        int first, int last) {
    __shared__ _Float16 lds[16384];   // 32KB: A 16 frags | Bh 8 | Bl 8 (512h each)

    const int tid = threadIdx.x;
    const int wave = tid >> 6, lane = tid & 63;
    const int wy = wave >> 1, wx = wave & 1;     // 4x2 wave grid
    const int ln = lane & 31, lh = lane >> 5;
    const int bid = blockIdx.x;
    const int b0 = (bid & 63) << 8;              // 64 row-tiles of 256
    const int n0 = (bid >> 6) << 7;              // 16 col-tiles of 128
    const int R0 = b0 >> 5, C0 = n0 >> 5;

    floatx16 acc[2][2] = {};

    // staging: 32 frags/chunk, 4 per wave.
    // waves 0-3 -> A frags 0..15; waves 4,5 -> Bh frags 16..23; 6,7 -> Bl 24..31
    const _Float16* plane = (wave < 4) ? Av : (wave < 6) ? Bth : Btl;
    const int T0 = (wave < 4) ? R0 : C0;
    const int tb = (wave < 4) ? 2 * wave : ((wave & 1) ? 2 : 0);
    const int f0 = 4 * wave;
    const _Float16* P = plane + ((size_t)(T0 + tb) * 32) * 512 + lane * 8;

    const int ro = lane << 3;            // lane-linear fragment read offset (halves)

    for (int c = 0; c < 16; ++c) {
        __syncthreads();                 // previous chunk's frag reads done
#pragma unroll
        for (int q = 0; q < 4; ++q) {    // q>>1 = tile step, q&1 = ktile
            gl_lds16(P + (size_t)(q >> 1) * (32 * 512) + (((2 * c) + (q & 1)) << 9),
                     lds + ((f0 + q) << 9));
        }
        __builtin_amdgcn_s_waitcnt(0);   // drain this wave's DMA
        __syncthreads();                 // all frags staged

#pragma unroll
        for (int ks = 0; ks < 2; ++ks) {
            half8 fa[2], fbh[2], fbl[2];
#pragma unroll
            for (int i = 0; i < 2; ++i) {
                const int sa = (((wy * 2 + i) << 1) + ks) << 9;
                const int sb = (((wx * 2 + i) << 1) + ks) << 9;
                fa[i]  = *(const half8*)(lds + sa + ro);
                fbh[i] = *(const half8*)(lds + 8192 + sb + ro);
                fbl[i] = *(const half8*)(lds + 12288 + sb + ro);
            }
#pragma unroll
            for (int j = 0; j < 2; ++j)
#pragma unroll
                for (int i = 0; i < 2; ++i) {
                    acc[i][j] = __builtin_amdgcn_mfma_f32_32x32x16_f16(fa[i], fbh[j], acc[i][j], 0, 0, 0);
                    acc[i][j] = __builtin_amdgcn_mfma_f32_32x32x16_f16(fa[i], fbl[j], acc[i][j], 0, 0, 0);
                }
        }
    }

    const float beta = beta_p[0];
    const float tc = gamma_p[0] * 0.044194173824159216f;   // gamma / sqrt(512)
#pragma unroll
    for (int i = 0; i < 2; ++i) {
#pragma unroll
        for (int reg = 0; reg < 16; ++reg) {
            const int rr = (reg & 3) + 8 * (reg >> 2) + 4 * lh;   // 0..31
            const int b = b0 + wy * 64 + i * 32 + rr;
            const float tb2 = tc * sqrtf(t2[b]);
            uint* arow = alphaP + (size_t)b * Nsz + n0 + wx * 64 + ln;
            float s = 0.f;
#pragma unroll
            for (int j = 0; j < 2; ++j) {
                float z = first ? 0.f : unpackHL(arow[j * 32]);
                float val = fmaxf(fmaf(beta, acc[i][j][reg], z) - tb2, 0.f);
                if (last) ((float*)arow)[j * 32] = val;   // final fp32, same 4-B slot
                else      arow[j * 32] = packHL(val);
                s = fmaf(val, val, s);
            }
            s += __shfl_down(s, 16, 32);
            s += __shfl_down(s, 8, 32);
            s += __shfl_down(s, 4, 32);
            s += __shfl_down(s, 2, 32);
            s += __shfl_down(s, 1, 32);
            if (ln == 0) atomicAdd(&na2[b], s);
        }
    }
}

// gemm2: v = y - beta*(alpha@D^T) + beta/512*sqrt(na2[b])*v_old; fused t2 atomic.
// 256x128 tile, 8 waves, grid 256 = 1 block/CU: no TLP available, so latency
// is hidden intra-block: 64KB double-buffer, 2-phase pipeline (T3) — issue
// STAGE(c+1) into buf^1 BEFORE compute(c), drain at chunk bottom so the
// ~1024-cyc MFMA span covers DMA latency. A regs prefetched 2 chunks ahead.
__global__ __launch_bounds__(512, 2) void gemm2_kernel(
        const uint* __restrict__ alphaP,
        const _Float16* __restrict__ Bh, const _Float16* __restrict__ Bl,
        const float* __restrict__ na2,
        const float* __restrict__ y,
        _Float16* __restrict__ vh,
        float* __restrict__ t2,
        const float* __restrict__ beta_p) {
    __shared__ _Float16 lds[32768];   // 64KB: 2 x (A 16 frags | Bh 8 | Bl 8)

    const int tid = threadIdx.x;
    const int wave = tid >> 6, lane = tid & 63;
    const int wy = wave >> 1, wx = wave & 1;
    const int ln = lane & 31, lh = lane >> 5;
    const int bid = blockIdx.x;
    const int b0 = (bid & 63) << 8;              // 64 row-tiles of 256
    const int m0 = (bid >> 6) << 7;              // 4 col-tiles of 128
    const int C0 = m0 >> 5;

    floatx16 acc[2][2] = {};

    // A staging: thread (srow, skq) covers one ktile-half of one row (16 words)
    const int srow = tid >> 1;                   // 0..255
    const int skq  = (tid & 1) << 4;
    const uint* apP = alphaP + (size_t)(b0 + srow) * Nsz + skq;
    // lane-linear frag layout: k&15 in 0..7 -> +0, 8..15 -> +256
    const int awo = ((((srow >> 5) << 1) + (skq >> 4)) << 9) + ((srow & 31) << 3);

    // B staging via gl_lds: waves 0-3 -> Bh ctile (wave&3); waves 4-7 -> Bl
    const _Float16* gB = ((wave < 4) ? Bh : Bl)
                       + ((size_t)(C0 + (wave & 3)) * 128) * 512 + lane * 8;
    const int fB = 16 + ((wave < 4) ? 0 : 8) + (wave & 3) * 2;

    const int ro = lane << 3;

    uint4 a0, a1, a2, a3;
    auto loadA = [&](int c) {
        const uint* nx = apP + c * 32;
        a0 = *(const uint4*)(nx);
        a1 = *(const uint4*)(nx + 4);
        a2 = *(const uint4*)(nx + 8);
        a3 = *(const uint4*)(nx + 12);
    };
    auto writeA = [&](int d) {      // extract hi (low16s) and ds_write in frag format
        uint4 ha, hb;
        ha.x = __builtin_amdgcn_perm(a0.y, a0.x, 0x05040100u);
        ha.y = __builtin_amdgcn_perm(a0.w, a0.z, 0x05040100u);
        ha.z = __builtin_amdgcn_perm(a1.y, a1.x, 0x05040100u);
        ha.w = __builtin_amdgcn_perm(a1.w, a1.z, 0x05040100u);
        hb.x = __builtin_amdgcn_perm(a2.y, a2.x, 0x05040100u);
        hb.y = __builtin_amdgcn_perm(a2.w, a2.z, 0x05040100u);
        hb.z = __builtin_amdgcn_perm(a3.y, a3.x, 0x05040100u);
        hb.w = __builtin_amdgcn_perm(a3.w, a3.z, 0x05040100u);
        _Float16* aw = lds + d * 16384 + awo;
        *(uint4*)aw = ha;
        *(uint4*)(aw + 256) = hb;
    };
    auto stageB = [&](int c, int d) {
        _Float16* lB = lds + d * 16384;
#pragma unroll
        for (int kt = 0; kt < 2; ++kt)
            gl_lds16(gB + (((size_t)2 * c + kt) << 9), lB + ((fB + kt) << 9));
    };

    loadA(0);
    writeA(0);
    stageB(0, 0);
    loadA(1);
    __builtin_amdgcn_s_waitcnt(0);
    __syncthreads();

    for (int c = 0; c < 64; ++c) {
        const int cur = c & 1;
        if (c < 63) {
            writeA(cur ^ 1);             // A(c+1) from regs (loaded 2 chunks back)
            stageB(c + 1, cur ^ 1);      // B DMA in flight under compute(c)
            if (c < 62) loadA(c + 2);    // A regs for next chunk's writeA
        }
        const _Float16* lb = lds + cur * 16384;
#pragma unroll
        for (int ks = 0; ks < 2; ++ks) {
            half8 fa[2], fbh[2], fbl[2];
#pragma unroll
            for (int i = 0; i < 2; ++i) {
                const int sa = (((wy * 2 + i) << 1) + ks) << 9;
                const int sb = (((wx * 2 + i) << 1) + ks) << 9;
                fa[i]  = *(const half8*)(lb + sa + ro);
                fbh[i] = *(const half8*)(lb + 8192 + sb + ro);
                fbl[i] = *(const half8*)(lb + 12288 + sb + ro);
            }
#pragma unroll
            for (int j = 0; j < 2; ++j)
#pragma unroll
                for (int i = 0; i < 2; ++i) {
                    acc[i][j] = __builtin_amdgcn_mfma_f32_32x32x16_f16(fa[i], fbh[j], acc[i][j], 0, 0, 0);
                    acc[i][j] = __builtin_amdgcn_mfma_f32_32x32x16_f16(fa[i], fbl[j], acc[i][j], 0, 0, 0);
                }
        }
        __builtin_amdgcn_s_waitcnt(0);   // prefetch had the whole MFMA span to land
        __syncthreads();
    }

    const float beta = beta_p[0];
#pragma unroll
    for (int i = 0; i < 2; ++i) {
#pragma unroll
        for (int reg = 0; reg < 16; ++reg) {
            const int rr = (reg & 3) + 8 * (reg >> 2) + 4 * lh;
            const int b = b0 + wy * 64 + i * 32 + rr;
            const float cb = beta * (1.0f / 512.0f) * sqrtf(na2[b]);
            float s = 0.f;
#pragma unroll
            for (int j = 0; j < 2; ++j) {
                const int m = m0 + wx * 64 + j * 32 + ln;
                const size_t po = ((size_t)(b >> 5) * 32 + (m >> 4)) * 512
                                + (((size_t)(m >> 3) & 1) << 8) + ((b & 31) << 3) + (m & 7);
                const size_t yi = (size_t)b * Msz + m;
                float vold = (float)vh[po];
                float val = y[yi] - beta * acc[i][j][reg] + cb * vold;
                vh[po] = (_Float16)val;
                s = fmaf(val, val, s);
            }
            s += __shfl_down(s, 16, 32);
            s += __shfl_down(s, 8, 32);
            s += __shfl_down(s, 4, 32);
            s += __shfl_down(s, 2, 32);
            s += __shfl_down(s, 1, 32);
            if (ln == 0) atomicAdd(&t2[b], s);
        }
    }
}

extern "C" void kernel_launch(void* const* d_in, const int* in_sizes, int n_in,
                              void* d_out, int out_size, void* d_ws, size_t ws_size,
                              hipStream_t stream) {
    (void)in_sizes; (void)n_in; (void)out_size; (void)ws_size;
    const float* batch   = (const float*)d_in[0];   // [B, M]
    const float* D       = (const float*)d_in[1];   // [M, N]
    const float* gamma_p = (const float*)d_in[2];   // scalar
    const float* beta_p  = (const float*)d_in[3];   // scalar

    uint* alphaP = (uint*)d_out;    // packed hi/lo per element (plain layout); fp32 after final iter

    // workspace (~27 MB)
    _Float16* vh   = (_Float16*)d_ws;               // [B*M] permuted, single plane
    _Float16* Dph  = vh + (size_t)Bsz * Msz;        // [M*N] permuted (gemm2 B)
    _Float16* Dpl  = Dph + (size_t)Msz * Nsz;
    _Float16* Dtph = Dpl + (size_t)Msz * Nsz;       // [N*M] permuted (gemm1 B)
    _Float16* Dtpl = Dtph + (size_t)Msz * Nsz;
    float*    t2s  = (float*)(Dtpl + (size_t)Msz * Nsz);   // [10][Bsz] sum v^2
    float*    na2s = t2s + 10 * Bsz;                        // [10][Bsz] sum alpha^2

    // zero t2 slabs 1..9 + na2 slabs 0..9 (contiguous 19*Bsz floats)
    zero_kernel<<<19 * Bsz / 1024, 256, 0, stream>>>((float4*)(t2s + Bsz));
    convD_kernel<<<dim3(Nsz / 64, Msz / 64), 256, 0, stream>>>(D, Dph, Dpl, Dtph, Dtpl);
    init_kernel<<<Bsz / 4, 256, 0, stream>>>(batch, vh, t2s);   // writes t2 slab 0

    for (int it = 0; it < 10; ++it) {
        gemm1_kernel<<<1024, 512, 0, stream>>>(vh, Dtph, Dtpl,
                                               t2s + (size_t)it * Bsz,
                                               alphaP,
                                               na2s + (size_t)it * Bsz,
                                               beta_p, gamma_p,
                                               it == 0 ? 1 : 0, it == 9 ? 1 : 0);
        if (it < 9) {   // last iteration's new_v is unused by the reference output
            gemm2_kernel<<<256, 512, 0, stream>>>(alphaP, Dph, Dpl,
                                                  na2s + (size_t)it * Bsz,
                                                  batch, vh,
                                                  t2s + (size_t)(it + 1) * Bsz,
                                                  beta_p);
        }
    }
}

// Round 4
// 2213.030 us; speedup vs baseline: 1.1372x; 1.0137x over previous
//
#include <hip/hip_runtime.h>
#include <math.h>

#define Bsz 16384
#define Msz 512
#define Nsz 2048

typedef _Float16 half8 __attribute__((ext_vector_type(8)));
typedef _Float16 half4 __attribute__((ext_vector_type(4)));
typedef _Float16 half2v __attribute__((ext_vector_type(2)));
typedef float floatx16 __attribute__((ext_vector_type(16)));
typedef unsigned int uint;

struct HL { _Float16 h, l; };
__device__ __forceinline__ HL split1(float x) {
    HL r;
    r.h = (_Float16)x;
    r.l = (_Float16)(x - (float)r.h);   // exact residual (two-term split)
    return r;
}
__device__ __forceinline__ uint packHL(float x) {
    HL s = split1(x);
    return (uint)__builtin_bit_cast(unsigned short, s.h)
         | ((uint)__builtin_bit_cast(unsigned short, s.l) << 16);
}
__device__ __forceinline__ float unpackHL(uint w) {
    half2v p = __builtin_bit_cast(half2v, w);
    return (float)p.x + (float)p.y;
}

// async global->LDS, 16B per lane. LDS dest = wave-uniform base + lane*16.
__device__ __forceinline__ void gl_lds16(const _Float16* g, _Float16* l) {
    __builtin_amdgcn_global_load_lds(
        (const __attribute__((address_space(1))) unsigned int*)g,
        (__attribute__((address_space(3))) unsigned int*)l, 16, 0, 0);
}

// raw barrier: no compiler-inserted vmcnt(0) drain (unlike __syncthreads).
// "memory" clobber = compiler fence so LDS/global ops can't cross.
#define BAR()  asm volatile("s_barrier" ::: "memory")

// fragment-permuted layout (32x32x16 MFMA), lane-linear (bank-conflict-free):
// element (r,k) of [R][K] at frag(r>>5, k>>4)*512
//                          + ((k>>3)&1)*256 + (r&31)*8 + (k&7)      [halves]
// => lane l's half8 operand (r=l&31, k=(l>>5)*8 ..+7) sits at frag*512 + l*8:
//    a wave's ds_read_b128 covers 1KB contiguous -> all 32 banks, conflict-free.

// zero 19*Bsz floats (t2 slabs 1..9 + na2 slabs 0..9, contiguous)
__global__ __launch_bounds__(256) void zero_kernel(float4* __restrict__ p) {
    p[blockIdx.x * 256 + threadIdx.x] = make_float4(0.f, 0.f, 0.f, 0.f);
}

// iter-0: v = batch -> single f16 permuted plane; t2s[0][b] = sum(v^2) (fp32).
__global__ __launch_bounds__(256) void init_kernel(const float* __restrict__ batch,
        _Float16* __restrict__ vh, float* __restrict__ t2) {
    const int wave = threadIdx.x >> 6;
    const int lane = threadIdx.x & 63;
    const int b = (blockIdx.x << 2) + wave;
    const float* row = batch + (size_t)b * Msz + lane * 8;
    float4 a = *(const float4*)row;
    float4 c = *(const float4*)(row + 4);
    half8 h;
    h[0] = (_Float16)a.x; h[1] = (_Float16)a.y;
    h[2] = (_Float16)a.z; h[3] = (_Float16)a.w;
    h[4] = (_Float16)c.x; h[5] = (_Float16)c.y;
    h[6] = (_Float16)c.z; h[7] = (_Float16)c.w;
    // m = lane*8: frag col = lane>>1, (k>>3)&1 = lane&1, k&7 = 0
    const size_t off = ((size_t)(b >> 5) * 32 + (lane >> 1)) * 512
                     + ((size_t)(lane & 1) << 8) + ((b & 31) << 3);
    *(half8*)(vh + off) = h;
    float s = a.x*a.x + a.y*a.y + a.z*a.z + a.w*a.w
            + c.x*c.x + c.y*c.y + c.z*c.z + c.w*c.w;
#pragma unroll
    for (int off2 = 32; off2 > 0; off2 >>= 1) s += __shfl_down(s, off2);
    if (lane == 0) t2[b] = s;
}

// One-time: D [M][N] fp32 -> Dperm hi/lo  (gemm2 B: r=m, k=n, K=2048)
//                        and Dtperm hi/lo (gemm1 B: r=n, k=m, K=512)
__global__ __launch_bounds__(256) void convD_kernel(const float* __restrict__ D,
        _Float16* __restrict__ Dph, _Float16* __restrict__ Dpl,
        _Float16* __restrict__ Dtph, _Float16* __restrict__ Dtpl) {
    __shared__ float T[64][65];
    const int t = threadIdx.x;
    const int tx = t & 15, ty = t >> 4;
    const int n0 = blockIdx.x << 6, m0 = blockIdx.y << 6;
#pragma unroll
    for (int q = 0; q < 4; ++q) {
        const int mr = m0 + (ty << 2) + q;
        const int nc = n0 + (tx << 2);
        float4 d = *(const float4*)(D + (size_t)mr * Nsz + nc);
        half4 h, l;
        HL s0 = split1(d.x), s1 = split1(d.y), s2 = split1(d.z), s3 = split1(d.w);
        h[0] = s0.h; l[0] = s0.l; h[1] = s1.h; l[1] = s1.l;
        h[2] = s2.h; l[2] = s2.l; h[3] = s3.h; l[3] = s3.l;
        // r=mr, k=nc (nc multiple of 4 -> 4 halves contiguous in k&7 group)
        const size_t o2 = ((size_t)(mr >> 5) * 128 + (nc >> 4)) * 512
                        + (((size_t)(nc >> 3) & 1) << 8) + ((mr & 31) << 3) + (nc & 7);
        *(half4*)(Dph + o2) = h;
        *(half4*)(Dpl + o2) = l;
        T[(tx << 2) + 0][(ty << 2) + q] = d.x;
        T[(tx << 2) + 1][(ty << 2) + q] = d.y;
        T[(tx << 2) + 2][(ty << 2) + q] = d.z;
        T[(tx << 2) + 3][(ty << 2) + q] = d.w;
    }
    __syncthreads();
#pragma unroll
    for (int q = 0; q < 4; ++q) {
        const int nr = n0 + (ty << 2) + q;
        const int mc = m0 + (tx << 2);
        float4 d = make_float4(T[(ty << 2) + q][tx << 2],
                               T[(ty << 2) + q][(tx << 2) + 1],
                               T[(ty << 2) + q][(tx << 2) + 2],
                               T[(ty << 2) + q][(tx << 2) + 3]);
        half4 h, l;
        HL s0 = split1(d.x), s1 = split1(d.y), s2 = split1(d.z), s3 = split1(d.w);
        h[0] = s0.h; l[0] = s0.l; h[1] = s1.h; l[1] = s1.l;
        h[2] = s2.h; l[2] = s2.l; h[3] = s3.h; l[3] = s3.l;
        // r=nr, k=mc
        const size_t o1 = ((size_t)(nr >> 5) * 32 + (mc >> 4)) * 512
                        + (((size_t)(mc >> 3) & 1) << 8) + ((nr & 31) << 3) + (mc & 7);
        *(half4*)(Dtph + o1) = h;
        *(half4*)(Dtpl + o1) = l;
    }
}

// gemm1: alpha = relu((first?0:alpha) + beta*(v@D) - t[b]); fused na2 atomic.
// 256x128 tile, 8 waves (4x2). T3+T4: 64KB double-buffer, raw s_barrier,
// counted vmcnt(4) in main loop (never 0) -> stage(c+2) stays in flight
// across barriers; stage(c+1) gets a full chunk of coverage.
__global__ __launch_bounds__(512, 4) void gemm1_kernel(
        const _Float16* __restrict__ Av,
        const _Float16* __restrict__ Bth, const _Float16* __restrict__ Btl,
        const float* __restrict__ t2,
        uint* __restrict__ alphaP,
        float* __restrict__ na2,
        const float* __restrict__ beta_p, const float* __restrict__ gamma_p,
        int first, int last) {
    __shared__ _Float16 lds[32768];   // 64KB: 2 x (A 16 frags | Bh 8 | Bl 8)

    const int tid = threadIdx.x;
    const int wave = tid >> 6, lane = tid & 63;
    const int wy = wave >> 1, wx = wave & 1;     // 4x2 wave grid
    const int ln = lane & 31, lh = lane >> 5;
    const int bid = blockIdx.x;
    const int b0 = (bid & 63) << 8;              // 64 row-tiles of 256
    const int n0 = (bid >> 6) << 7;              // 16 col-tiles of 128
    const int R0 = b0 >> 5, C0 = n0 >> 5;

    floatx16 acc[2][2] = {};

    // staging: 32 frags/chunk, 4 per wave (all 8 waves issue exactly 4 gl_lds).
    // waves 0-3 -> A frags 0..15; waves 4,5 -> Bh frags 16..23; 6,7 -> Bl 24..31
    const _Float16* plane = (wave < 4) ? Av : (wave < 6) ? Bth : Btl;
    const int T0 = (wave < 4) ? R0 : C0;
    const int tb = (wave < 4) ? 2 * wave : ((wave & 1) ? 2 : 0);
    const int f0 = 4 * wave;
    const _Float16* P = plane + ((size_t)(T0 + tb) * 32) * 512 + lane * 8;

    const int ro = lane << 3;            // lane-linear fragment read offset (halves)

    auto stage = [&](int c, int d) {
        _Float16* lp = lds + d * 16384;
#pragma unroll
        for (int q = 0; q < 4; ++q) {    // q>>1 = tile step, q&1 = ktile
            gl_lds16(P + (size_t)(q >> 1) * (32 * 512) + (((2 * c) + (q & 1)) << 9),
                     lp + ((f0 + q) << 9));
        }
    };

    // prologue: chunk0 -> buf0 (drained), chunk1 -> buf1 (left in flight)
    stage(0, 0);
    stage(1, 1);
    asm volatile("s_waitcnt vmcnt(4)" ::: "memory");   // own stage(0) done
    BAR();                                             // all waves' stage(0) done

    for (int c = 0; c < 16; ++c) {
        const _Float16* lb = lds + (c & 1) * 16384;
        __builtin_amdgcn_s_setprio(1);
#pragma unroll
        for (int ks = 0; ks < 2; ++ks) {
            half8 fa[2], fbh[2], fbl[2];
#pragma unroll
            for (int i = 0; i < 2; ++i) {
                const int sa = (((wy * 2 + i) << 1) + ks) << 9;
                const int sb = (((wx * 2 + i) << 1) + ks) << 9;
                fa[i]  = *(const half8*)(lb + sa + ro);
                fbh[i] = *(const half8*)(lb + 8192 + sb + ro);
                fbl[i] = *(const half8*)(lb + 12288 + sb + ro);
            }
#pragma unroll
            for (int j = 0; j < 2; ++j)
#pragma unroll
                for (int i = 0; i < 2; ++i) {
                    acc[i][j] = __builtin_amdgcn_mfma_f32_32x32x16_f16(fa[i], fbh[j], acc[i][j], 0, 0, 0);
                    acc[i][j] = __builtin_amdgcn_mfma_f32_32x32x16_f16(fa[i], fbl[j], acc[i][j], 0, 0, 0);
                }
        }
        __builtin_amdgcn_s_setprio(0);
        if (c == 15) break;
        BAR();                           // readers of buf[c&1] done (WAR vs stage(c+2))
        if (c + 2 < 16) {
            stage(c + 2, c & 1);
            asm volatile("s_waitcnt vmcnt(4)" ::: "memory");  // own stage(c+1) done; c+2 flies
        } else {
            asm volatile("s_waitcnt vmcnt(0)" ::: "memory");  // tail: stage(15) done
        }
        BAR();                           // all waves' stage(c+1) published
    }

    const float beta = beta_p[0];
    const float tc = gamma_p[0] * 0.044194173824159216f;   // gamma / sqrt(512)
#pragma unroll
    for (int i = 0; i < 2; ++i) {
#pragma unroll
        for (int reg = 0; reg < 16; ++reg) {
            const int rr = (reg & 3) + 8 * (reg >> 2) + 4 * lh;   // 0..31
            const int b = b0 + wy * 64 + i * 32 + rr;
            const float tb2 = tc * sqrtf(t2[b]);
            uint* arow = alphaP + (size_t)b * Nsz + n0 + wx * 64 + ln;
            float s = 0.f;
#pragma unroll
            for (int j = 0; j < 2; ++j) {
                float z = first ? 0.f : unpackHL(arow[j * 32]);
                float val = fmaxf(fmaf(beta, acc[i][j][reg], z) - tb2, 0.f);
                if (last) ((float*)arow)[j * 32] = val;   // final fp32, same 4-B slot
                else      arow[j * 32] = packHL(val);
                s = fmaf(val, val, s);
            }
            s += __shfl_down(s, 16, 32);
            s += __shfl_down(s, 8, 32);
            s += __shfl_down(s, 4, 32);
            s += __shfl_down(s, 2, 32);
            s += __shfl_down(s, 1, 32);
            if (ln == 0) atomicAdd(&na2[b], s);
        }
    }
}

// gemm2: v = y - beta*(alpha@D^T) + beta/512*sqrt(na2[b])*v_old; fused t2 atomic.
// 256x128 tile, 8 waves, grid 256 (1 block/CU). T3+T4 as gemm1: raw barriers,
// counted vmcnt(6) (2 gl_lds B-stage + 4 A-reg loads stay in flight),
// lgkmcnt(0) before closing barrier commits A ds_writes. A regs: load(c+3),
// write(c+2), so each leg gets >= one full chunk of latency coverage.
__global__ __launch_bounds__(512, 2) void gemm2_kernel(
        const uint* __restrict__ alphaP,
        const _Float16* __restrict__ Bh, const _Float16* __restrict__ Bl,
        const float* __restrict__ na2,
        const float* __restrict__ y,
        _Float16* __restrict__ vh,
        float* __restrict__ t2,
        const float* __restrict__ beta_p) {
    __shared__ _Float16 lds[32768];   // 64KB: 2 x (A 16 frags | Bh 8 | Bl 8)

    const int tid = threadIdx.x;
    const int wave = tid >> 6, lane = tid & 63;
    const int wy = wave >> 1, wx = wave & 1;
    const int ln = lane & 31, lh = lane >> 5;
    const int bid = blockIdx.x;
    const int b0 = (bid & 63) << 8;              // 64 row-tiles of 256
    const int m0 = (bid >> 6) << 7;              // 4 col-tiles of 128
    const int C0 = m0 >> 5;

    floatx16 acc[2][2] = {};

    // A staging: thread (srow, skq) covers one ktile-half of one row (16 words)
    const int srow = tid >> 1;                   // 0..255
    const int skq  = (tid & 1) << 4;
    const uint* apP = alphaP + (size_t)(b0 + srow) * Nsz + skq;
    // lane-linear frag layout: k&15 in 0..7 -> +0, 8..15 -> +256
    const int awo = ((((srow >> 5) << 1) + (skq >> 4)) << 9) + ((srow & 31) << 3);

    // B staging via gl_lds: waves 0-3 -> Bh ctile (wave&3); waves 4-7 -> Bl
    const _Float16* gB = ((wave < 4) ? Bh : Bl)
                       + ((size_t)(C0 + (wave & 3)) * 128) * 512 + lane * 8;
    const int fB = 16 + ((wave < 4) ? 0 : 8) + (wave & 3) * 2;

    const int ro = lane << 3;

    uint4 a0, a1, a2, a3;
    auto loadA = [&](int c) {
        const uint* nx = apP + c * 32;
        a0 = *(const uint4*)(nx);
        a1 = *(const uint4*)(nx + 4);
        a2 = *(const uint4*)(nx + 8);
        a3 = *(const uint4*)(nx + 12);
    };
    auto writeA = [&](int d) {      // extract hi (low16s) and ds_write in frag format
        uint4 ha, hb;
        ha.x = __builtin_amdgcn_perm(a0.y, a0.x, 0x05040100u);
        ha.y = __builtin_amdgcn_perm(a0.w, a0.z, 0x05040100u);
        ha.z = __builtin_amdgcn_perm(a1.y, a1.x, 0x05040100u);
        ha.w = __builtin_amdgcn_perm(a1.w, a1.z, 0x05040100u);
        hb.x = __builtin_amdgcn_perm(a2.y, a2.x, 0x05040100u);
        hb.y = __builtin_amdgcn_perm(a2.w, a2.z, 0x05040100u);
        hb.z = __builtin_amdgcn_perm(a3.y, a3.x, 0x05040100u);
        hb.w = __builtin_amdgcn_perm(a3.w, a3.z, 0x05040100u);
        _Float16* aw = lds + d * 16384 + awo;
        *(uint4*)aw = ha;
        *(uint4*)(aw + 256) = hb;
    };
    auto stageB = [&](int c, int d) {
        _Float16* lB = lds + d * 16384;
#pragma unroll
        for (int kt = 0; kt < 2; ++kt)
            gl_lds16(gB + (((size_t)2 * c + kt) << 9), lB + ((fB + kt) << 9));
    };

    // prologue: buf0 complete; buf1 B in flight + A written; regs hold A(2)
    loadA(0);
    writeA(0);
    stageB(0, 0);
    loadA(1);
    writeA(1);            // auto vmcnt wait drains loadA(1) (and older stageB(0))
    stageB(1, 1);
    loadA(2);
    asm volatile("s_waitcnt vmcnt(6) lgkmcnt(0)" ::: "memory");
    BAR();

    for (int c = 0; c < 64; ++c) {
        const _Float16* lb = lds + (c & 1) * 16384;
        __builtin_amdgcn_s_setprio(1);
#pragma unroll
        for (int ks = 0; ks < 2; ++ks) {
            half8 fa[2], fbh[2], fbl[2];
#pragma unroll
            for (int i = 0; i < 2; ++i) {
                const int sa = (((wy * 2 + i) << 1) + ks) << 9;
                const int sb = (((wx * 2 + i) << 1) + ks) << 9;
                fa[i]  = *(const half8*)(lb + sa + ro);
                fbh[i] = *(const half8*)(lb + 8192 + sb + ro);
                fbl[i] = *(const half8*)(lb + 12288 + sb + ro);
            }
#pragma unroll
            for (int j = 0; j < 2; ++j)
#pragma unroll
                for (int i = 0; i < 2; ++i) {
                    acc[i][j] = __builtin_amdgcn_mfma_f32_32x32x16_f16(fa[i], fbh[j], acc[i][j], 0, 0, 0);
                    acc[i][j] = __builtin_amdgcn_mfma_f32_32x32x16_f16(fa[i], fbl[j], acc[i][j], 0, 0, 0);
                }
        }
        __builtin_amdgcn_s_setprio(0);
        if (c == 63) break;
        BAR();                           // readers of buf[c&1] done
        if (c < 61) {
            stageB(c + 2, c & 1);        // B(c+2) flies across the barrier
            writeA(c & 1);               // A(c+2); auto-wait drains loadA(c+2)+stageB(c+1)
            loadA(c + 3);                // A regs for next chunk's writeA
            asm volatile("s_waitcnt vmcnt(6) lgkmcnt(0)" ::: "memory");
        } else if (c == 61) {
            stageB(63, 1);
            writeA(1);                   // A(63)
            asm volatile("s_waitcnt vmcnt(2) lgkmcnt(0)" ::: "memory");
        } else {                         // c == 62: drain stage(63)
            asm volatile("s_waitcnt vmcnt(0) lgkmcnt(0)" ::: "memory");
        }
        BAR();                           // buf[(c+1)&1] published
    }

    const float beta = beta_p[0];
#pragma unroll
    for (int i = 0; i < 2; ++i) {
#pragma unroll
        for (int reg = 0; reg < 16; ++reg) {
            const int rr = (reg & 3) + 8 * (reg >> 2) + 4 * lh;
            const int b = b0 + wy * 64 + i * 32 + rr;
            const float cb = beta * (1.0f / 512.0f) * sqrtf(na2[b]);
            float s = 0.f;
#pragma unroll
            for (int j = 0; j < 2; ++j) {
                const int m = m0 + wx * 64 + j * 32 + ln;
                const size_t po = ((size_t)(b >> 5) * 32 + (m >> 4)) * 512
                                + (((size_t)(m >> 3) & 1) << 8) + ((b & 31) << 3) + (m & 7);
                const size_t yi = (size_t)b * Msz + m;
                float vold = (float)vh[po];
                float val = y[yi] - beta * acc[i][j][reg] + cb * vold;
                vh[po] = (_Float16)val;
                s = fmaf(val, val, s);
            }
            s += __shfl_down(s, 16, 32);
            s += __shfl_down(s, 8, 32);
            s += __shfl_down(s, 4, 32);
            s += __shfl_down(s, 2, 32);
            s += __shfl_down(s, 1, 32);
            if (ln == 0) atomicAdd(&t2[b], s);
        }
    }
}

extern "C" void kernel_launch(void* const* d_in, const int* in_sizes, int n_in,
                              void* d_out, int out_size, void* d_ws, size_t ws_size,
                              hipStream_t stream) {
    (void)in_sizes; (void)n_in; (void)out_size; (void)ws_size;
    const float* batch   = (const float*)d_in[0];   // [B, M]
    const float* D       = (const float*)d_in[1];   // [M, N]
    const float* gamma_p = (const float*)d_in[2];   // scalar
    const float* beta_p  = (const float*)d_in[3];   // scalar

    uint* alphaP = (uint*)d_out;    // packed hi/lo per element (plain layout); fp32 after final iter

    // workspace (~27 MB)
    _Float16* vh   = (_Float16*)d_ws;               // [B*M] permuted, single plane
    _Float16* Dph  = vh + (size_t)Bsz * Msz;        // [M*N] permuted (gemm2 B)
    _Float16* Dpl  = Dph + (size_t)Msz * Nsz;
    _Float16* Dtph = Dpl + (size_t)Msz * Nsz;       // [N*M] permuted (gemm1 B)
    _Float16* Dtpl = Dtph + (size_t)Msz * Nsz;
    float*    t2s  = (float*)(Dtpl + (size_t)Msz * Nsz);   // [10][Bsz] sum v^2
    float*    na2s = t2s + 10 * Bsz;                        // [10][Bsz] sum alpha^2

    // zero t2 slabs 1..9 + na2 slabs 0..9 (contiguous 19*Bsz floats)
    zero_kernel<<<19 * Bsz / 1024, 256, 0, stream>>>((float4*)(t2s + Bsz));
    convD_kernel<<<dim3(Nsz / 64, Msz / 64), 256, 0, stream>>>(D, Dph, Dpl, Dtph, Dtpl);
    init_kernel<<<Bsz / 4, 256, 0, stream>>>(batch, vh, t2s);   // writes t2 slab 0

    for (int it = 0; it < 10; ++it) {
        gemm1_kernel<<<1024, 512, 0, stream>>>(vh, Dtph, Dtpl,
                                               t2s + (size_t)it * Bsz,
                                               alphaP,
                                               na2s + (size_t)it * Bsz,
                                               beta_p, gamma_p,
                                               it == 0 ? 1 : 0, it == 9 ? 1 : 0);
        if (it < 9) {   // last iteration's new_v is unused by the reference output
            gemm2_kernel<<<256, 512, 0, stream>>>(alphaP, Dph, Dpl,
                                                  na2s + (size_t)it * Bsz,
                                                  batch, vh,
                                                  t2s + (size_t)(it + 1) * Bsz,
                                                  beta_p);
        }
    }
}